// Round 2
// baseline (230.480 us; speedup 1.0000x reference)
//
#include <hip/hip_runtime.h>

#define Bdim   4096
#define INdim  4096
#define OUTdim 2048
#define Knz    32

// f32 -> bf16 round-to-nearest-even
__device__ inline unsigned short f2bf(float f) {
  unsigned u = __float_as_uint(f);
  u += 0x7fffu + ((u >> 16) & 1u);
  return (unsigned short)(u >> 16);
}

// Kernel 1: xT[i][b] = bf16(x[b][i]).  64x64 tiles via LDS.  ~96 MB @ HBM ceiling.
__global__ __launch_bounds__(256) void k_transpose(const float* __restrict__ x,
                                                   unsigned short* __restrict__ xT) {
  __shared__ float tile[64][65];
  const int bi = blockIdx.x;      // 64-row tile (b dim)
  const int ii = blockIdx.y;      // 64-col tile (IN dim)
  const int t = threadIdx.x;
  const int r = t >> 4;           // 0..15
  const int c = t & 15;           // 0..15
#pragma unroll
  for (int rr = 0; rr < 64; rr += 16) {
    const float4 v = *reinterpret_cast<const float4*>(
        &x[(size_t)(bi * 64 + rr + r) * INdim + ii * 64 + c * 4]);
    tile[rr + r][c * 4 + 0] = v.x;
    tile[rr + r][c * 4 + 1] = v.y;
    tile[rr + r][c * 4 + 2] = v.z;
    tile[rr + r][c * 4 + 3] = v.w;
  }
  __syncthreads();
#pragma unroll
  for (int rr = 0; rr < 64; rr += 16) {
    const int il = rr + r;
    ushort4 o;
    o.x = f2bf(tile[c * 4 + 0][il]);
    o.y = f2bf(tile[c * 4 + 1][il]);
    o.z = f2bf(tile[c * 4 + 2][il]);
    o.w = f2bf(tile[c * 4 + 3][il]);
    *reinterpret_cast<ushort4*>(
        &xT[(size_t)(ii * 64 + il) * Bdim + bi * 64 + c * 4]) = o;
  }
}

// Kernel 2: gather-dot.
// Lane owns 4 consecutive b (dwordx2 gathers, 512B/wave-instr).
// Block: 256-b slice x 16-o panel (full 64B out-line per row per block).
// 16 b-slices of 2MB; XCD x processes slice x (first 128 of its blocks),
// then slice x+8 -> per-XCD L2 working set = 2MB (half of L2).
__global__ __launch_bounds__(256, 4) void k_gather(const unsigned short* __restrict__ xT,
                                                   const int* __restrict__ cols,
                                                   const float* __restrict__ values,
                                                   float* __restrict__ out) {
  const int wg = blockIdx.x;           // 0..2047
  const int xcd = wg & 7;
  const int g = wg >> 3;               // 0..255 per XCD
  const int bb = xcd + 8 * (g >> 7);   // phase-ordered 2MB slices
  const int obg = g & 127;             // 128 o-groups of 16
  const int w = threadIdx.x >> 6;      // wave 0..3 -> 4 consecutive o
  const int l = threadIdx.x & 63;      // lane -> 4 consecutive b
  const int b0 = bb * 256 + l * 4;
  const int o0 = obg * 16 + w * 4;

  float acc[4][4];                     // [oc][b-sub], fully unrolled -> registers
#pragma unroll
  for (int i = 0; i < 4; ++i)
#pragma unroll
    for (int j = 0; j < 4; ++j) acc[i][j] = 0.f;

#pragma unroll
  for (int oc = 0; oc < 4; ++oc) {
    const int o = o0 + oc;
    const int* __restrict__ cp = cols + o * Knz;
    const float* __restrict__ vp = values + o * Knz;
#pragma unroll
    for (int k = 0; k < Knz; ++k) {
      const int col = cp[k];           // uniform -> s_load
      const float val = vp[k];         // uniform -> s_load
      const uint2 u = *reinterpret_cast<const uint2*>(
          &xT[(size_t)col * Bdim + b0]);                 // coalesced 8B/lane
      acc[oc][0] = fmaf(__uint_as_float(u.x << 16), val, acc[oc][0]);
      acc[oc][1] = fmaf(__uint_as_float(u.x & 0xffff0000u), val, acc[oc][1]);
      acc[oc][2] = fmaf(__uint_as_float(u.y << 16), val, acc[oc][2]);
      acc[oc][3] = fmaf(__uint_as_float(u.y & 0xffff0000u), val, acc[oc][3]);
    }
  }

#pragma unroll
  for (int r = 0; r < 4; ++r) {
    *reinterpret_cast<float4*>(&out[(size_t)(b0 + r) * OUTdim + o0]) =
        make_float4(acc[0][r], acc[1][r], acc[2][r], acc[3][r]);
  }
}

// Correct-but-slow fallback if ws can't hold xT (32 MB).
__global__ __launch_bounds__(256) void k_naive(const float* __restrict__ x,
                                               const float* __restrict__ values,
                                               const int* __restrict__ cols,
                                               float* __restrict__ out) {
  const size_t id = (size_t)blockIdx.x * 256 + threadIdx.x;
  const int o = (int)(id % OUTdim);
  const int b = (int)(id / OUTdim);
  float a = 0.f;
  for (int k = 0; k < Knz; ++k) {
    const int col = cols[o * Knz + k];
    a = fmaf(x[(size_t)b * INdim + col], values[o * Knz + k], a);
  }
  out[id] = a;
}

extern "C" void kernel_launch(void* const* d_in, const int* in_sizes, int n_in,
                              void* d_out, int out_size, void* d_ws, size_t ws_size,
                              hipStream_t stream) {
  const float* x = (const float*)d_in[0];
  const float* values = (const float*)d_in[1];
  const int* cols = (const int*)d_in[2];
  float* out = (float*)d_out;

  const size_t need = (size_t)INdim * Bdim * sizeof(unsigned short);  // 32 MB
  if (ws_size >= need) {
    unsigned short* xT = (unsigned short*)d_ws;
    k_transpose<<<dim3(64, 64), 256, 0, stream>>>(x, xT);
    k_gather<<<2048, 256, 0, stream>>>(xT, cols, values, out);
  } else {
    k_naive<<<(Bdim * (size_t)OUTdim) / 256, 256, 0, stream>>>(x, values, cols, out);
  }
}

// Round 3
// 229.049 us; speedup vs baseline: 1.0062x; 1.0062x over previous
//
#include <hip/hip_runtime.h>

#define Bdim   4096
#define INdim  4096
#define OUTdim 2048
#define Knz    32

typedef float  f4  __attribute__((ext_vector_type(4)));
typedef short  s4  __attribute__((ext_vector_type(4)));

// f32 -> bf16 round-to-nearest-even
__device__ inline unsigned short f2bf(float f) {
  unsigned u = __float_as_uint(f);
  u += 0x7fffu + ((u >> 16) & 1u);
  return (unsigned short)(u >> 16);
}

// Kernel 1: xT[i][b] = bf16(x[b][i]).  64x64 tiles via LDS.  ~96 MB stream at HBM BW.
// nt on both sides: neither x nor xT should pollute L2 (gather re-fetches its slice once).
__global__ __launch_bounds__(256) void k_transpose(const float* __restrict__ x,
                                                   unsigned short* __restrict__ xT) {
  __shared__ float tile[64][65];
  const int bi = blockIdx.x;      // 64-row tile (b dim)
  const int ii = blockIdx.y;      // 64-col tile (IN dim)
  const int t = threadIdx.x;
  const int r = t >> 4;           // 0..15
  const int c = t & 15;           // 0..15
#pragma unroll
  for (int rr = 0; rr < 64; rr += 16) {
    const f4 v = __builtin_nontemporal_load(reinterpret_cast<const f4*>(
        &x[(size_t)(bi * 64 + rr + r) * INdim + ii * 64 + c * 4]));
    tile[rr + r][c * 4 + 0] = v.x;
    tile[rr + r][c * 4 + 1] = v.y;
    tile[rr + r][c * 4 + 2] = v.z;
    tile[rr + r][c * 4 + 3] = v.w;
  }
  __syncthreads();
#pragma unroll
  for (int rr = 0; rr < 64; rr += 16) {
    const int il = rr + r;
    s4 o;
    o.x = (short)f2bf(tile[c * 4 + 0][il]);
    o.y = (short)f2bf(tile[c * 4 + 1][il]);
    o.z = (short)f2bf(tile[c * 4 + 2][il]);
    o.w = (short)f2bf(tile[c * 4 + 3][il]);
    __builtin_nontemporal_store(o, reinterpret_cast<s4*>(
        &xT[(size_t)(ii * 64 + il) * Bdim + bi * 64 + c * 4]));
  }
}

// Kernel 2: gather-dot.
// 1024 blocks: bb = wg&7 (XCD-pinned 4MB xT slice, round-robin dispatch),
// o-panel = wg>>3 in [0,128), 16 outputs per block.
// Thread: 2 consecutive b (dword gathers, uniform col -> s_load) x 16 o.
// Output: each thread owns FULL 64B lines of out, stored non-temporally so the
// write stream never evicts the xT slice from L2.
__global__ __launch_bounds__(256) void k_gather(const unsigned short* __restrict__ xT,
                                                const int* __restrict__ cols,
                                                const float* __restrict__ values,
                                                float* __restrict__ out) {
  const int wg = blockIdx.x;           // 0..1023
  const int bb = wg & 7;               // slice == XCD
  const int op = wg >> 3;              // 0..127
  const int t = threadIdx.x;
  const int b0 = bb * 512 + t * 2;     // two consecutive b per thread
  const int o0 = op * 16;

  float acc[16][2];                    // [oc][b-sub] — fully unrolled -> registers
#pragma unroll
  for (int oc = 0; oc < 16; ++oc) { acc[oc][0] = 0.f; acc[oc][1] = 0.f; }

#pragma unroll
  for (int oc = 0; oc < 16; ++oc) {
    const int o = o0 + oc;
    const int* __restrict__ cp = cols + o * Knz;
    const float* __restrict__ vp = values + o * Knz;
    float a0 = 0.f, a1 = 0.f;
#pragma unroll
    for (int k = 0; k < Knz; ++k) {
      const int col = cp[k];           // wave-uniform -> s_load
      const float val = vp[k];         // wave-uniform -> s_load
      const unsigned u = *reinterpret_cast<const unsigned*>(
          &xT[(size_t)col * Bdim + b0]);                 // coalesced 4B/lane, L2-resident
      a0 = fmaf(__uint_as_float(u << 16), val, a0);
      a1 = fmaf(__uint_as_float(u & 0xffff0000u), val, a1);
    }
    acc[oc][0] = a0;
    acc[oc][1] = a1;
  }

  // Two full 64B out-lines per thread, non-temporal.
#pragma unroll
  for (int r = 0; r < 2; ++r) {
    float* rowp = &out[(size_t)(b0 + r) * OUTdim + o0];
#pragma unroll
    for (int j = 0; j < 4; ++j) {
      f4 v;
      v.x = acc[4 * j + 0][r];
      v.y = acc[4 * j + 1][r];
      v.z = acc[4 * j + 2][r];
      v.w = acc[4 * j + 3][r];
      __builtin_nontemporal_store(v, reinterpret_cast<f4*>(rowp + 4 * j));
    }
  }
}

// Correct-but-slow fallback if ws can't hold xT (32 MB).
__global__ __launch_bounds__(256) void k_naive(const float* __restrict__ x,
                                               const float* __restrict__ values,
                                               const int* __restrict__ cols,
                                               float* __restrict__ out) {
  const size_t id = (size_t)blockIdx.x * 256 + threadIdx.x;
  const int o = (int)(id % OUTdim);
  const int b = (int)(id / OUTdim);
  float a = 0.f;
  for (int k = 0; k < Knz; ++k) {
    const int col = cols[o * Knz + k];
    a = fmaf(x[(size_t)b * INdim + col], values[o * Knz + k], a);
  }
  out[id] = a;
}

extern "C" void kernel_launch(void* const* d_in, const int* in_sizes, int n_in,
                              void* d_out, int out_size, void* d_ws, size_t ws_size,
                              hipStream_t stream) {
  const float* x = (const float*)d_in[0];
  const float* values = (const float*)d_in[1];
  const int* cols = (const int*)d_in[2];
  float* out = (float*)d_out;

  const size_t need = (size_t)INdim * Bdim * sizeof(unsigned short);  // 32 MB
  if (ws_size >= need) {
    unsigned short* xT = (unsigned short*)d_ws;
    k_transpose<<<dim3(64, 64), 256, 0, stream>>>(x, xT);
    k_gather<<<1024, 256, 0, stream>>>(xT, cols, values, out);
  } else {
    k_naive<<<(Bdim * (size_t)OUTdim) / 256, 256, 0, stream>>>(x, values, cols, out);
  }
}